// Round 5
// baseline (71724.341 us; speedup 1.0000x reference)
//
#include <hip/hip_runtime.h>
#include <hip/hip_fp16.h>

// LSTM_54537494725306: 2-layer LSTM, T=2048, D=512, H=2048, OUT=64, fp32 in/out.
// R7 = R6 structure with the launch fixed. R6's cooperative launch of 512 WGs
// almost certainly FAILED validation: __launch_bounds__(512,2) means 2 waves/EU
// = 1 block/CU (reg cap 256, allocator used >128 VGPRs) -> only 256 WGs can
// co-reside -> hipLaunchCooperativeKernel error (unchecked) -> zero output
// (absmax 6.5e-2 == scale of max|y|).
// Fixes:
//   * __launch_bounds__(512, 4): 4 waves/EU -> 2 blocks/CU -> 128-VGPR cap.
//     R6's K-split design needs only ~72 weight regs + ~40 working < 128.
//   * hipLaunchCooperativeKernel return code CHECKED; on failure fall back to
//     the proven R2-style fp16 streaming persistent kernel (256 WGs).
// Design recap (R6): 2 waves per unit (K-split halves), 512 WGs x 8 waves.
//   per wave: Wih2 half-rows 32 reg + Whh2 32 reg + Wih1 quarter-rows 8 reg.
//   LDS/WG: Whh1 for 4 units (64 KB) + 128 B cross-half partial buffer.
//   Halves combine via LDS + one __syncthreads; c1/c2 live in half-0 waves.
// Math: same fp16->f32 cvt -> f32 fmaf chains as R2-R5 (absmax 4.9e-4 there).

#define T_STEPS 2048
#define DIM_D   512
#define DIM_H   2048
#define DIM_OUT 64
#define NWG     512
#define NTHR    512
#define UPW     4      // units per workgroup

#define N_WIH1 (4 * DIM_H * DIM_D)   //  4,194,304
#define N_WHH1 (4 * DIM_H * DIM_H)   // 16,777,216
#define N_WIH2 (4 * DIM_H * DIM_H)
#define N_WHH2 (4 * DIM_H * DIM_H)
#define N_WLIN (DIM_OUT * DIM_H)     //    131,072
#define WS_WEIGHT_OFF 65536

__device__ __forceinline__ float sigf(float x)   { return 1.0f / (1.0f + __expf(-x)); }
__device__ __forceinline__ float tanh_f(float x) { return 1.0f - 2.0f / (__expf(2.0f * x) + 1.0f); }

__device__ __forceinline__ float wave_reduce(float v) {
#pragma unroll
    for (int off = 32; off > 0; off >>= 1) v += __shfl_xor(v, off, 64);
    return v;
}

struct F8 { float4 a, b; };

__device__ __forceinline__ F8 load8(const float* __restrict__ p, int e) {
    F8 r;
    const float4* q = (const float4*)(p + e);
    r.a = q[0]; r.b = q[1];
    return r;
}

__device__ __forceinline__ F8 cvt8(uint4 u) {
    float2 f0 = __half22float2(*(__half2*)&u.x);
    float2 f1 = __half22float2(*(__half2*)&u.y);
    float2 f2 = __half22float2(*(__half2*)&u.z);
    float2 f3 = __half22float2(*(__half2*)&u.w);
    F8 r;
    r.a = make_float4(f0.x, f0.y, f1.x, f1.y);
    r.b = make_float4(f2.x, f2.y, f3.x, f3.y);
    return r;
}

__device__ __forceinline__ F8 load8(const __half* __restrict__ p, int e) {
    uint4 u = *(const uint4*)(p + e);
    return cvt8(u);
}

__device__ __forceinline__ float dot8(const F8& v, const F8& w, float acc) {
    acc = fmaf(v.a.x, w.a.x, acc); acc = fmaf(v.a.y, w.a.y, acc);
    acc = fmaf(v.a.z, w.a.z, acc); acc = fmaf(v.a.w, w.a.w, acc);
    acc = fmaf(v.b.x, w.b.x, acc); acc = fmaf(v.b.y, w.b.y, acc);
    acc = fmaf(v.b.z, w.b.z, acc); acc = fmaf(v.b.w, w.b.w, acc);
    return acc;
}

// 4-row dot over K elements (streaming fallback path only).
template<int K, typename WT>
__device__ __forceinline__ void dot4(const float* __restrict__ v,
                                     const WT* __restrict__ w0, const WT* __restrict__ w1,
                                     const WT* __restrict__ w2, const WT* __restrict__ w3,
                                     int lane, float& a0, float& a1, float& a2, float& a3) {
#pragma unroll
    for (int i = 0; i < K / 512; ++i) {
        const int e = (lane + 64 * i) * 8;
        const F8 vv = load8(v, e);
        a0 = dot8(vv, load8(w0, e), a0);
        a1 = dot8(vv, load8(w1, e), a1);
        a2 = dot8(vv, load8(w2, e), a2);
        a3 = dot8(vv, load8(w3, e), a3);
    }
}

// Two-level sense-free barrier over NGRP*32 workgroups.
template<int NGRP>
__device__ __forceinline__ void grid_barrier(int* bar, int wg, int g) {
    __syncthreads();
    if (threadIdx.x == 0) {
        const int grp = wg >> 5;
        int a = __hip_atomic_fetch_add(&bar[grp * 32], 1, __ATOMIC_ACQ_REL, __HIP_MEMORY_SCOPE_AGENT);
        if (a == 31) {
            int r = __hip_atomic_fetch_add(&bar[NGRP * 32], 1, __ATOMIC_ACQ_REL, __HIP_MEMORY_SCOPE_AGENT);
            if (r == NGRP - 1) {
#pragma unroll
                for (int i = 0; i < NGRP; ++i)
                    __hip_atomic_store(&bar[i * 32], 0, __ATOMIC_RELAXED, __HIP_MEMORY_SCOPE_AGENT);
                __hip_atomic_store(&bar[NGRP * 32], 0, __ATOMIC_RELAXED, __HIP_MEMORY_SCOPE_AGENT);
                __hip_atomic_store(&bar[NGRP * 32 + 32], g + 1, __ATOMIC_RELEASE, __HIP_MEMORY_SCOPE_AGENT);
            }
        }
        while (__hip_atomic_load(&bar[NGRP * 32 + 32], __ATOMIC_RELAXED, __HIP_MEMORY_SCOPE_AGENT) <= g) {
            __builtin_amdgcn_s_sleep(2);
        }
        __builtin_amdgcn_fence(__ATOMIC_ACQUIRE, "agent");
    }
    __syncthreads();
}

__global__ void lstm_init(int* bar, float* h1buf, float* h2buf) {
    int i = threadIdx.x + blockIdx.x * blockDim.x;
    if (i < 1024) bar[i] = 0;
    if (i < 2 * DIM_H) { h1buf[i] = 0.0f; h2buf[i] = 0.0f; }
}

// fp32 -> fp16 (RNE), 4 elements/thread.
__global__ void convert_f16(const float* __restrict__ src, __half* __restrict__ dst, int n4) {
    int i = threadIdx.x + blockIdx.x * blockDim.x;
    if (i < n4) {
        float4 f = ((const float4*)src)[i];
        __half2 h01 = __floats2half2_rn(f.x, f.y);
        __half2 h23 = __floats2half2_rn(f.z, f.w);
        uint2 o;
        o.x = *(unsigned int*)&h01;
        o.y = *(unsigned int*)&h23;
        ((uint2*)dst)[i] = o;
    }
}

// ---------------------------------------------------------------------------
// Main path. 512 WGs x 8 waves. Wave (ul, half): ul = wave>>1 in [0,4),
// half = wave&1. unit = wg*4 + ul. Each half-wave owns K-range
// [half*1024, +1024) of the unit's layer-2 rows and [half*256,+256) of x /
// [half*1024,+1024) of h for layer 1.
// __launch_bounds__(512,4): 4 waves/EU -> 2 blocks/CU -> hard 128-VGPR cap.
// ---------------------------------------------------------------------------
__global__ __launch_bounds__(NTHR, 4) void lstm_resident(
    const float* __restrict__ x,
    const __half* __restrict__ Wih1, const __half* __restrict__ Whh1,
    const float* __restrict__ bih1, const float* __restrict__ bhh1,
    const __half* __restrict__ Wih2, const __half* __restrict__ Whh2,
    const float* __restrict__ bih2, const float* __restrict__ bhh2,
    const __half* __restrict__ Wlin, const float* __restrict__ blin,
    float* __restrict__ out,
    int* bar, float* h1buf, float* h2buf)
{
    const int wg   = blockIdx.x;
    const int wave = threadIdx.x >> 6;
    const int lane = threadIdx.x & 63;
    const int ul   = wave >> 1;
    const int half = wave & 1;
    const int unit = wg * UPW + ul;

    __shared__ uint4 ldsW[UPW][4][DIM_H / 8];   // Whh1: 65536 B
    __shared__ float ldsP[UPW][8];              // cross-half partials: 128 B

    const int r0 = unit, r1 = DIM_H + unit, r2 = 2 * DIM_H + unit, r3 = 3 * DIM_H + unit;

    const float b1_0 = bih1[r0] + bhh1[r0];
    const float b1_1 = bih1[r1] + bhh1[r1];
    const float b1_2 = bih1[r2] + bhh1[r2];
    const float b1_3 = bih1[r3] + bhh1[r3];
    const float b2_0 = bih2[r0] + bhh2[r0];
    const float b2_1 = bih2[r1] + bhh2[r1];
    const float b2_2 = bih2[r2] + bhh2[r2];
    const float b2_3 = bih2[r3] + bhh2[r3];

    // ---------------- one-time weight residency ----------------
    uint4 wI2[4][2], wH2[4][2];   // 64 VGPRs
    uint2 wI1[4];                 //  8 VGPRs
#pragma unroll
    for (int r = 0; r < 4; ++r) {
        const int row = r * DIM_H + unit;
        const uint4* bi = (const uint4*)(Wih2 + (size_t)row * DIM_H + half * 1024);
        const uint4* bh = (const uint4*)(Whh2 + (size_t)row * DIM_H + half * 1024);
#pragma unroll
        for (int j = 0; j < 2; ++j) {
            wI2[r][j] = bi[lane + 64 * j];
            wH2[r][j] = bh[lane + 64 * j];
        }
        wI1[r] = *(const uint2*)(Wih1 + (size_t)row * DIM_D + half * 256 + lane * 4);
        const uint4* q = (const uint4*)(Whh1 + (size_t)row * DIM_H + half * 1024);
#pragma unroll
        for (int j = 0; j < 2; ++j)
            ldsW[ul][r][half * 128 + lane + 64 * j] = q[lane + 64 * j];
    }
    __syncthreads();

    const bool  do_y = (wg < DIM_OUT) && (wave == 1);
    const float by   = (wg < DIM_OUT) ? blin[wg] : 0.0f;
    const __half* wy = Wlin + (size_t)(wg < DIM_OUT ? wg : 0) * DIM_H;

    float c1 = 0.0f, c2 = 0.0f;

    for (int p = 0; p < T_STEPS + 2; ++p) {
        const float* h1_prev  = h1buf + (size_t)((p + 1) & 1) * DIM_H;  // h1[p-1]
        float*       h1_cur   = h1buf + (size_t)(p & 1) * DIM_H;        // h1[p]
        const float* h2_prev2 = h2buf + (size_t)(p & 1) * DIM_H;        // h2[p-2]
        float*       h2_cur   = h2buf + (size_t)((p + 1) & 1) * DIM_H;  // h2[p-1]

        const bool doL1 = (p < T_STEPS);
        const bool doL2 = (p >= 1 && p <= T_STEPS);

        float aL1_0 = 0.f, aL1_1 = 0.f, aL1_2 = 0.f, aL1_3 = 0.f;
        float aL2_0 = 0.f, aL2_1 = 0.f, aL2_2 = 0.f, aL2_3 = 0.f;

        // ---- layer 1 x-part (256 cols/half, 4 floats/lane) ----
        if (doL1) {
            const float4 xv = *(const float4*)(x + (size_t)p * DIM_D + half * 256 + lane * 4);
            {
                const float2 f0 = __half22float2(*(__half2*)&wI1[0].x);
                const float2 f1 = __half22float2(*(__half2*)&wI1[0].y);
                aL1_0 = fmaf(xv.x, f0.x, aL1_0); aL1_0 = fmaf(xv.y, f0.y, aL1_0);
                aL1_0 = fmaf(xv.z, f1.x, aL1_0); aL1_0 = fmaf(xv.w, f1.y, aL1_0);
            }
            {
                const float2 f0 = __half22float2(*(__half2*)&wI1[1].x);
                const float2 f1 = __half22float2(*(__half2*)&wI1[1].y);
                aL1_1 = fmaf(xv.x, f0.x, aL1_1); aL1_1 = fmaf(xv.y, f0.y, aL1_1);
                aL1_1 = fmaf(xv.z, f1.x, aL1_1); aL1_1 = fmaf(xv.w, f1.y, aL1_1);
            }
            {
                const float2 f0 = __half22float2(*(__half2*)&wI1[2].x);
                const float2 f1 = __half22float2(*(__half2*)&wI1[2].y);
                aL1_2 = fmaf(xv.x, f0.x, aL1_2); aL1_2 = fmaf(xv.y, f0.y, aL1_2);
                aL1_2 = fmaf(xv.z, f1.x, aL1_2); aL1_2 = fmaf(xv.w, f1.y, aL1_2);
            }
            {
                const float2 f0 = __half22float2(*(__half2*)&wI1[3].x);
                const float2 f1 = __half22float2(*(__half2*)&wI1[3].y);
                aL1_3 = fmaf(xv.x, f0.x, aL1_3); aL1_3 = fmaf(xv.y, f0.y, aL1_3);
                aL1_3 = fmaf(xv.z, f1.x, aL1_3); aL1_3 = fmaf(xv.w, f1.y, aL1_3);
            }
        }

        // ---- shared h1_prev chunks: L1 (LDS Whh1) + L2 (VGPR Wih2) ----
#pragma unroll
        for (int j = 0; j < 2; ++j) {
            const F8 v = load8(h1_prev + half * 1024, (lane + 64 * j) * 8);
            if (doL1) {
                aL1_0 = dot8(v, cvt8(ldsW[ul][0][half * 128 + lane + 64 * j]), aL1_0);
                aL1_1 = dot8(v, cvt8(ldsW[ul][1][half * 128 + lane + 64 * j]), aL1_1);
                aL1_2 = dot8(v, cvt8(ldsW[ul][2][half * 128 + lane + 64 * j]), aL1_2);
                aL1_3 = dot8(v, cvt8(ldsW[ul][3][half * 128 + lane + 64 * j]), aL1_3);
            }
            if (doL2) {
                aL2_0 = dot8(v, cvt8(wI2[0][j]), aL2_0);
                aL2_1 = dot8(v, cvt8(wI2[1][j]), aL2_1);
                aL2_2 = dot8(v, cvt8(wI2[2][j]), aL2_2);
                aL2_3 = dot8(v, cvt8(wI2[3][j]), aL2_3);
            }
        }

        // ---- layer 2 h2_prev2 part ----
        if (doL2) {
#pragma unroll
            for (int j = 0; j < 2; ++j) {
                const F8 u = load8(h2_prev2 + half * 1024, (lane + 64 * j) * 8);
                aL2_0 = dot8(u, cvt8(wH2[0][j]), aL2_0);
                aL2_1 = dot8(u, cvt8(wH2[1][j]), aL2_1);
                aL2_2 = dot8(u, cvt8(wH2[2][j]), aL2_2);
                aL2_3 = dot8(u, cvt8(wH2[3][j]), aL2_3);
            }
        }

        // ---- intra-wave reduce, cross-half combine ----
        if (doL1) {
            aL1_0 = wave_reduce(aL1_0); aL1_1 = wave_reduce(aL1_1);
            aL1_2 = wave_reduce(aL1_2); aL1_3 = wave_reduce(aL1_3);
        }
        if (doL2) {
            aL2_0 = wave_reduce(aL2_0); aL2_1 = wave_reduce(aL2_1);
            aL2_2 = wave_reduce(aL2_2); aL2_3 = wave_reduce(aL2_3);
        }
        if (half == 1 && lane == 0) {
            ldsP[ul][0] = aL1_0; ldsP[ul][1] = aL1_1;
            ldsP[ul][2] = aL1_2; ldsP[ul][3] = aL1_3;
            ldsP[ul][4] = aL2_0; ldsP[ul][5] = aL2_1;
            ldsP[ul][6] = aL2_2; ldsP[ul][7] = aL2_3;
        }
        __syncthreads();

        if (half == 0) {
            if (doL1) {
                const float gi = sigf ((aL1_0 + ldsP[ul][0]) + b1_0);
                const float gf = sigf ((aL1_1 + ldsP[ul][1]) + b1_1);
                const float gg = tanh_f((aL1_2 + ldsP[ul][2]) + b1_2);
                const float go = sigf ((aL1_3 + ldsP[ul][3]) + b1_3);
                c1 = fmaf(gf, c1, gi * gg);
                if (lane == 0) h1_cur[unit] = go * tanh_f(c1);
            }
            if (doL2) {
                const float gi = sigf ((aL2_0 + ldsP[ul][4]) + b2_0);
                const float gf = sigf ((aL2_1 + ldsP[ul][5]) + b2_1);
                const float gg = tanh_f((aL2_2 + ldsP[ul][6]) + b2_2);
                const float go = sigf ((aL2_3 + ldsP[ul][7]) + b2_3);
                c2 = fmaf(gf, c2, gi * gg);
                if (lane == 0) h2_cur[unit] = go * tanh_f(c2);
            }
        }

        // ---- y, step p-2 (wave 1 of first 64 WGs) ----
        if (do_y && p >= 2) {
            float a = 0.f;
#pragma unroll
            for (int i = 0; i < DIM_H / 512; ++i) {
                const int e = (lane + 64 * i) * 8;
                a = dot8(load8(h2_prev2, e), load8(wy, e), a);
            }
            a = wave_reduce(a);
            if (lane == 0) out[(size_t)(p - 2) * DIM_OUT + wg] = a + by;
        }

        grid_barrier<16>(bar, wg, p);
    }
}

// ---------------------------------------------------------------------------
// Fallback: R2-style weight streaming, 256 WGs x 8 waves (proven correct).
// Used if workspace too small (WT=float) or if the cooperative launch of the
// resident kernel fails validation (WT=__half).
// ---------------------------------------------------------------------------
template<typename WT>
__global__ __launch_bounds__(NTHR, 2) void lstm_stream(
    const float* __restrict__ x,
    const WT* __restrict__ Wih1, const WT* __restrict__ Whh1,
    const float* __restrict__ bih1, const float* __restrict__ bhh1,
    const WT* __restrict__ Wih2, const WT* __restrict__ Whh2,
    const float* __restrict__ bih2, const float* __restrict__ bhh2,
    const WT* __restrict__ Wlin, const float* __restrict__ blin,
    float* __restrict__ out,
    int* bar, float* h1buf, float* h2buf)
{
    const int wg   = blockIdx.x;
    const int wave = threadIdx.x >> 6;
    const int lane = threadIdx.x & 63;
    const int unit = wg * 8 + wave;

    const int r0 = unit, r1 = DIM_H + unit, r2 = 2 * DIM_H + unit, r3 = 3 * DIM_H + unit;
    const float b1_0 = bih1[r0] + bhh1[r0];
    const float b1_1 = bih1[r1] + bhh1[r1];
    const float b1_2 = bih1[r2] + bhh1[r2];
    const float b1_3 = bih1[r3] + bhh1[r3];
    const float b2_0 = bih2[r0] + bhh2[r0];
    const float b2_1 = bih2[r1] + bhh2[r1];
    const float b2_2 = bih2[r2] + bhh2[r2];
    const float b2_3 = bih2[r3] + bhh2[r3];

    const WT* wi1_0 = Wih1 + (size_t)r0 * DIM_D;
    const WT* wi1_1 = Wih1 + (size_t)r1 * DIM_D;
    const WT* wi1_2 = Wih1 + (size_t)r2 * DIM_D;
    const WT* wi1_3 = Wih1 + (size_t)r3 * DIM_D;
    const WT* wh1_0 = Whh1 + (size_t)r0 * DIM_H;
    const WT* wh1_1 = Whh1 + (size_t)r1 * DIM_H;
    const WT* wh1_2 = Whh1 + (size_t)r2 * DIM_H;
    const WT* wh1_3 = Whh1 + (size_t)r3 * DIM_H;
    const WT* wi2_0 = Wih2 + (size_t)r0 * DIM_H;
    const WT* wi2_1 = Wih2 + (size_t)r1 * DIM_H;
    const WT* wi2_2 = Wih2 + (size_t)r2 * DIM_H;
    const WT* wi2_3 = Wih2 + (size_t)r3 * DIM_H;
    const WT* wh2_0 = Whh2 + (size_t)r0 * DIM_H;
    const WT* wh2_1 = Whh2 + (size_t)r1 * DIM_H;
    const WT* wh2_2 = Whh2 + (size_t)r2 * DIM_H;
    const WT* wh2_3 = Whh2 + (size_t)r3 * DIM_H;

    const bool  do_y = (wg < DIM_OUT) && (wave == 0);
    const float by   = (wg < DIM_OUT) ? blin[wg] : 0.0f;
    const WT*   wy   = Wlin + (size_t)(wg < DIM_OUT ? wg : 0) * DIM_H;

    float c1 = 0.0f, c2 = 0.0f;

    for (int p = 0; p < T_STEPS + 2; ++p) {
        const float* h1_prev  = h1buf + (size_t)((p + 1) & 1) * DIM_H;
        float*       h1_cur   = h1buf + (size_t)(p & 1) * DIM_H;
        const float* h2_prev2 = h2buf + (size_t)(p & 1) * DIM_H;
        float*       h2_cur   = h2buf + (size_t)((p + 1) & 1) * DIM_H;

        if (p < T_STEPS) {
            float a0 = 0.f, a1 = 0.f, a2 = 0.f, a3 = 0.f;
            dot4<DIM_D>(x + (size_t)p * DIM_D, wi1_0, wi1_1, wi1_2, wi1_3, lane, a0, a1, a2, a3);
            dot4<DIM_H>(h1_prev, wh1_0, wh1_1, wh1_2, wh1_3, lane, a0, a1, a2, a3);
            a0 = wave_reduce(a0); a1 = wave_reduce(a1);
            a2 = wave_reduce(a2); a3 = wave_reduce(a3);
            const float gi = sigf(a0 + b1_0);
            const float gf = sigf(a1 + b1_1);
            const float gg = tanh_f(a2 + b1_2);
            const float go = sigf(a3 + b1_3);
            c1 = fmaf(gf, c1, gi * gg);
            if (lane == 0) h1_cur[unit] = go * tanh_f(c1);
        }

        if (p >= 1 && p <= T_STEPS) {
            float a0 = 0.f, a1 = 0.f, a2 = 0.f, a3 = 0.f;
            dot4<DIM_H>(h1_prev,  wi2_0, wi2_1, wi2_2, wi2_3, lane, a0, a1, a2, a3);
            dot4<DIM_H>(h2_prev2, wh2_0, wh2_1, wh2_2, wh2_3, lane, a0, a1, a2, a3);
            a0 = wave_reduce(a0); a1 = wave_reduce(a1);
            a2 = wave_reduce(a2); a3 = wave_reduce(a3);
            const float gi = sigf(a0 + b2_0);
            const float gf = sigf(a1 + b2_1);
            const float gg = tanh_f(a2 + b2_2);
            const float go = sigf(a3 + b2_3);
            c2 = fmaf(gf, c2, gi * gg);
            if (lane == 0) h2_cur[unit] = go * tanh_f(c2);
        }

        if (do_y && p >= 2) {
            float a = 0.f;
#pragma unroll
            for (int i = 0; i < DIM_H / 512; ++i) {
                const int e = (lane + 64 * i) * 8;
                a = dot8(load8(h2_prev2, e), load8(wy, e), a);
            }
            a = wave_reduce(a);
            if (lane == 0) out[(size_t)(p - 2) * DIM_OUT + wg] = a + by;
        }

        grid_barrier<8>(bar, wg, p);
    }
}

extern "C" void kernel_launch(void* const* d_in, const int* in_sizes, int n_in,
                              void* d_out, int out_size, void* d_ws, size_t ws_size,
                              hipStream_t stream) {
    const float* x    = (const float*)d_in[0];
    const float* Wih1 = (const float*)d_in[1];
    const float* Whh1 = (const float*)d_in[2];
    const float* bih1 = (const float*)d_in[3];
    const float* bhh1 = (const float*)d_in[4];
    const float* Wih2 = (const float*)d_in[5];
    const float* Whh2 = (const float*)d_in[6];
    const float* bih2 = (const float*)d_in[7];
    const float* bhh2 = (const float*)d_in[8];
    const float* Wlin = (const float*)d_in[9];
    const float* blin = (const float*)d_in[10];
    float* out = (float*)d_out;

    int*   bar   = (int*)d_ws;
    float* h1buf = (float*)((char*)d_ws + 4096);
    float* h2buf = h1buf + 2 * DIM_H;

    lstm_init<<<16, 256, 0, stream>>>(bar, h1buf, h2buf);

    const size_t nweights = (size_t)N_WIH1 + N_WHH1 + N_WIH2 + N_WHH2 + N_WLIN;
    const size_t need = WS_WEIGHT_OFF + sizeof(__half) * nweights;

    if (ws_size >= need) {
        __half* hWih1 = (__half*)((char*)d_ws + WS_WEIGHT_OFF);
        __half* hWhh1 = hWih1 + N_WIH1;
        __half* hWih2 = hWhh1 + N_WHH1;
        __half* hWhh2 = hWih2 + N_WIH2;
        __half* hWlin = hWhh2 + N_WHH2;

        const float* srcs[5] = { Wih1, Whh1, Wih2, Whh2, Wlin };
        __half*      dsts[5] = { hWih1, hWhh1, hWih2, hWhh2, hWlin };
        const int    ns[5]   = { N_WIH1, N_WHH1, N_WIH2, N_WHH2, N_WLIN };
        for (int m = 0; m < 5; ++m) {
            int n4 = ns[m] / 4;
            convert_f16<<<(n4 + 255) / 256, 256, 0, stream>>>(srcs[m], dsts[m], n4);
        }

        const __half* cWih1 = hWih1; const __half* cWhh1 = hWhh1;
        const __half* cWih2 = hWih2; const __half* cWhh2 = hWhh2;
        const __half* cWlin = hWlin;
        void* args[] = {
            (void*)&x,
            (void*)&cWih1, (void*)&cWhh1, (void*)&bih1, (void*)&bhh1,
            (void*)&cWih2, (void*)&cWhh2, (void*)&bih2, (void*)&bhh2,
            (void*)&cWlin, (void*)&blin,
            (void*)&out, (void*)&bar, (void*)&h1buf, (void*)&h2buf
        };
        hipError_t e = hipLaunchCooperativeKernel((const void*)lstm_resident,
                                                  dim3(NWG), dim3(NTHR), args, 0, stream);
        if (e != hipSuccess) {
            // Co-residency validation failed: fall back to the proven fp16
            // streaming persistent kernel (256 WGs, 8 waves, grid_barrier<8>).
            hipLaunchCooperativeKernel((const void*)lstm_stream<__half>,
                                       dim3(256), dim3(NTHR), args, 0, stream);
        }
    } else {
        void* args[] = {
            (void*)&x,
            (void*)&Wih1, (void*)&Whh1, (void*)&bih1, (void*)&bhh1,
            (void*)&Wih2, (void*)&Whh2, (void*)&bih2, (void*)&bhh2,
            (void*)&Wlin, (void*)&blin,
            (void*)&out, (void*)&bar, (void*)&h1buf, (void*)&h2buf
        };
        hipLaunchCooperativeKernel((const void*)lstm_stream<float>,
                                   dim3(256), dim3(NTHR), args, 0, stream);
    }
}